// Round 4
// baseline (348.879 us; speedup 1.0000x reference)
//
#include <hip/hip_runtime.h>

#define SEQ 1024
#define BATCH 512
#define NTAGS 64
#define HALF_T 512
#define LOGD 4.158883083f   // log(64): per-step damp folded into exp(em)

typedef _Float16 v2h __attribute__((ext_vector_type(2)));

__device__ __forceinline__ float dot2acc(v2h a, v2h b, float c) {
#if __has_builtin(__builtin_amdgcn_fdot2)
    return __builtin_amdgcn_fdot2(a, b, c, false);
#else
    return fmaf((float)a.x, (float)b.x, fmaf((float)a.y, (float)b.y, c));
#endif
}

__device__ __forceinline__ float rfl(float x) {
    return __uint_as_float(__builtin_amdgcn_readfirstlane(__float_as_uint(x)));
}

template<int CTRL>
__device__ __forceinline__ unsigned dppmov(unsigned v) {
    return (unsigned)__builtin_amdgcn_mov_dpp((int)v, CTRL, 0xf, 0xf, false);
}

// Pair across the 32-lane boundary: after this, {a,b} hold {x_l, x_{l^32}}
// in a lane-dependent order. Order is irrelevant: the weight layout is
// derived by running the IDENTICAL ops on lane indices at init.
// NOTE: builtin returns a NATIVE vector (vector_size(8)) -> index with [0]/[1].
__device__ __forceinline__ void swap32pair(unsigned x, unsigned& a, unsigned& b) {
#if __has_builtin(__builtin_amdgcn_permlane32_swap)
    auto r = __builtin_amdgcn_permlane32_swap(x, x, false, false);
    a = (unsigned)r[0]; b = (unsigned)r[1];
#else
    a = x; b = (unsigned)__shfl_xor((int)x, 32);
#endif
}

__device__ __forceinline__ void swap16pair(unsigned x, unsigned& a, unsigned& b) {
#if __has_builtin(__builtin_amdgcn_permlane16_swap)
    auto r = __builtin_amdgcn_permlane16_swap(x, x, false, false);
    a = (unsigned)r[0]; b = (unsigned)r[1];
#else
    a = x; b = (unsigned)__shfl_xor((int)x, 16);
#endif
}

// Doubling butterfly: 1 packed reg (2 vals) -> 32 regs (all 64 vals).
// Levels: 16-swap, row-shift DPP ctrls, quad_perm xor2 (0x4E),
// quad_perm xor1 (0xB1). Delivery order is lane-dependent but mirrored
// exactly by the index butterfly at init.
__device__ __forceinline__ void expand64(unsigned p0, unsigned u[32]) {
    swap16pair(p0, u[0], u[1]);
    u[2] = dppmov<0x140>(u[0]);
    u[3] = dppmov<0x140>(u[1]);
#pragma unroll
    for (int k = 0; k < 4; ++k)  u[4 + k]  = dppmov<0x141>(u[k]);
#pragma unroll
    for (int k = 0; k < 8; ++k)  u[8 + k]  = dppmov<0x4E>(u[k]);
#pragma unroll
    for (int k = 0; k < 16; ++k) u[16 + k] = dppmov<0xB1>(u[k]);
}

// Broadcast one fp32 per lane -> 32 fp16-pair regs holding all 64 lanes' values.
__device__ __forceinline__ void bcast64(float x, v2h p[32]) {
    unsigned a, b;
    swap32pair(__float_as_uint(x), a, b);
#if __has_builtin(__builtin_amdgcn_cvt_pkrtz)
    auto pk_ = __builtin_amdgcn_cvt_pkrtz(__uint_as_float(a), __uint_as_float(b));
    unsigned pk = __builtin_bit_cast(unsigned, pk_);
#else
    v2h pkv; pkv.x = (_Float16)__uint_as_float(a); pkv.y = (_Float16)__uint_as_float(b);
    unsigned pk = __builtin_bit_cast(unsigned, pkv);
#endif
    unsigned u[32];
    expand64(pk, u);
#pragma unroll
    for (int s = 0; s < 32; ++s) p[s] = __builtin_bit_cast(v2h, u[s]);
}

// Fused CRF kernel: block b runs BOTH chains of batch b.
//   wave0 (fwd): t = 1..min(L-1,511);  wave1 (bwd): t = L-1..512 descending.
// The per-step 64-wide broadcast is a pure-VALU butterfly (permlane+DPP),
// no LDS on the critical path. Weight layout matches the butterfly's
// delivery order by running the same butterfly on lane indices at init.
__global__ __launch_bounds__(128)
void crf_kernel(const float* __restrict__ em,
                const int* __restrict__ tags,
                const int* __restrict__ mask,
                const float* __restrict__ startT,
                const float* __restrict__ endT,
                const float* __restrict__ trans,
                float* __restrict__ out)
{
    const int  b   = blockIdx.x;
    const int  wid = threadIdx.x >> 6;
    const int  j   = threadIdx.x & 63;
    const bool fwd = (wid == 0);

    __shared__ float gsh[NTAGS];   // gamma from bwd wave
    __shared__ float mb_np[2];     // [0]=Mb, [1]=np partial (bwd)

    // chain length = sum of this batch's mask column
    int lsum = 0;
#pragma unroll
    for (int k = 0; k < SEQ / 64; ++k)
        lsum += mask[(k * 64 + j) * BATCH + b];
#pragma unroll
    for (int off = 32; off > 0; off >>= 1)
        lsum += __shfl_xor(lsum, off);
    const int L = lsum;

    // Index butterfly: find which beta-index lands in each slot/component.
    unsigned I[32];
    {
        unsigned ia, ib;
        swap32pair((unsigned)j, ia, ib);
        unsigned i0 = (ia & 0xffffu) | (ib << 16);
        expand64(i0, I);
    }

    // fp16 expT fragment matched to the butterfly delivery order:
    // fwd lane j needs column j (T[i][j]); bwd lane j needs row j (T[j][i]).
    v2h w[32];
#pragma unroll
    for (int s = 0; s < 32; ++s) {
        unsigned i0 = I[s] & 0xffffu;
        unsigned i1 = I[s] >> 16;
        float a0 = fwd ? trans[i0 * NTAGS + j] : trans[j * NTAGS + i0];
        float a1 = fwd ? trans[i1 * NTAGS + j] : trans[j * NTAGS + i1];
        v2h t; t.x = (_Float16)__expf(a0); t.y = (_Float16)__expf(a1);
        w[s] = t;
    }

#define DOT(WRVAL, SOUT)                                                   \
    {                                                                      \
        v2h p_[32];                                                        \
        bcast64((WRVAL), p_);                                              \
        float s0 = 0.f, s1 = 0.f, s2 = 0.f, s3 = 0.f;                      \
        float s4 = 0.f, s5 = 0.f, s6 = 0.f, s7 = 0.f;                      \
        _Pragma("unroll")                                                  \
        for (int q = 0; q < 4; ++q) {                                      \
            s0 = dot2acc(p_[8 * q + 0], w[8 * q + 0], s0);                 \
            s1 = dot2acc(p_[8 * q + 1], w[8 * q + 1], s1);                 \
            s2 = dot2acc(p_[8 * q + 2], w[8 * q + 2], s2);                 \
            s3 = dot2acc(p_[8 * q + 3], w[8 * q + 3], s3);                 \
            s4 = dot2acc(p_[8 * q + 4], w[8 * q + 4], s4);                 \
            s5 = dot2acc(p_[8 * q + 5], w[8 * q + 5], s5);                 \
            s6 = dot2acc(p_[8 * q + 6], w[8 * q + 6], s6);                 \
            s7 = dot2acc(p_[8 * q + 7], w[8 * q + 7], s7);                 \
        }                                                                  \
        SOUT = ((s0 + s1) + (s2 + s3)) + ((s4 + s5) + (s6 + s7));          \
    }

    float beta, M;
    int nsteps = 0;

    if (fwd) {
        float em0 = em[(size_t)b * NTAGS + j];
        float a0  = startT[j] + em0;
        M    = __shfl(a0, 0);
        beta = __expf(a0 - M);

        const int Lf = min(L - 1, HALF_T - 1);   // active steps t=1..Lf
        int t = 1;
        float cur[4], nxt[4];
#pragma unroll
        for (int u = 0; u < 4; ++u) {
            cur[u] = em[((size_t)min(t + u,     SEQ - 1) * BATCH + b) * NTAGS + j];
            nxt[u] = em[((size_t)min(t + 4 + u, SEQ - 1) * BATCH + b) * NTAGS + j];
        }
        while (t + 3 <= Lf) {
            float pre[4];
#pragma unroll
            for (int u = 0; u < 4; ++u)
                pre[u] = em[((size_t)min(t + 8 + u, SEQ - 1) * BATCH + b) * NTAGS + j];
            float eem[4];
#pragma unroll
            for (int u = 0; u < 4; ++u) eem[u] = __expf(cur[u] - LOGD);

            float s;
            DOT(beta, s); beta = s * eem[0];
            DOT(beta, s);
            float r = rfl(s);                 // uniform-ish positive renorm scale
            beta = s * eem[1];
            DOT(beta, s); beta = s * eem[2];
            float rinv = 1.0f / r;            // off-path
            float lr   = __logf(r);           // off-path
            DOT(beta, s); beta = s * (eem[3] * rinv);
            M += lr;
            nsteps += 4;
#pragma unroll
            for (int u = 0; u < 4; ++u) { cur[u] = nxt[u]; nxt[u] = pre[u]; }
            t += 4;
        }
        for (; t <= Lf; ++t) {
            float emt = em[((size_t)t * BATCH + b) * NTAGS + j];
            float s; DOT(beta, s);
            beta = s * __expf(emt - LOGD);
            ++nsteps;
        }
    } else {
        beta = __expf(endT[j]);               // B_j init (frozen for t >= L)
        M = 0.0f;
        if (L - 1 >= HALF_T) {
            int tt = L - 1;                   // steps tt = L-1 .. 512 descending
            float cur[4], nxt[4];
#pragma unroll
            for (int u = 0; u < 4; ++u) {
                cur[u] = em[((size_t)max(tt - u,     0) * BATCH + b) * NTAGS + j];
                nxt[u] = em[((size_t)max(tt - 4 - u, 0) * BATCH + b) * NTAGS + j];
            }
            while (tt - 3 >= HALF_T) {
                float pre[4];
#pragma unroll
                for (int u = 0; u < 4; ++u)
                    pre[u] = em[((size_t)max(tt - 8 - u, 0) * BATCH + b) * NTAGS + j];
                float eem[4];
#pragma unroll
                for (int u = 0; u < 4; ++u) eem[u] = __expf(cur[u] - LOGD);

                float s;
                DOT(beta * eem[0], s); beta = s;
                DOT(beta * eem[1], s);
                float r = rfl(s);
                beta = s;
                DOT(beta * eem[2], s); beta = s;
                float rinv = 1.0f / r;
                float lr   = __logf(r);
                DOT(beta * (eem[3] * rinv), s); beta = s;
                M += lr;
                nsteps += 4;
#pragma unroll
                for (int u = 0; u < 4; ++u) { cur[u] = nxt[u]; nxt[u] = pre[u]; }
                tt -= 4;
            }
            for (; tt >= HALF_T; --tt) {
                float emt = em[((size_t)tt * BATCH + b) * NTAGS + j];
                float s; DOT(beta * __expf(emt - LOGD), s);
                beta = s;
                ++nsteps;
            }
        }
    }
#undef DOT

    const float Mfb = fmaf((float)nsteps, LOGD, M);  // per-wave log-scale

    if (!fwd) {
        gsh[j] = beta;                      // gamma vector
        if (j == 0) mb_np[0] = Mfb;         // Mb
    }

    // numerator partial: thread tid handles t = k*128 + tid
    float np = 0.0f;
#pragma unroll
    for (int k = 0; k < SEQ / 128; ++k) {
        int t = k * 128 + wid * 64 + j;
        if (t >= 1 && t < L) {
            int ct = tags[t * BATCH + b];
            int pt = tags[(t - 1) * BATCH + b];
            np += trans[pt * NTAGS + ct] + em[((size_t)t * BATCH + b) * NTAGS + ct];
        }
    }
    if (threadIdx.x == 0) {
        int t0 = tags[b];
        np += startT[t0] + em[(size_t)b * NTAGS + t0]
            + endT[tags[(size_t)(L - 1) * BATCH + b]];
    }
#pragma unroll
    for (int off = 32; off > 0; off >>= 1)
        np += __shfl_xor(np, off);
    if (!fwd && j == 0) mb_np[1] = np;

    __syncthreads();

    if (fwd) {
        float p = beta * gsh[j];            // midpoint dot: beta_f . gamma
#pragma unroll
        for (int off = 32; off > 0; off >>= 1)
            p += __shfl_xor(p, off);
        if (j == 0) {
            float denom = __logf(p) + Mfb + mb_np[0];
            atomicAdd(out, (np + mb_np[1]) - denom);
        }
    }
}

extern "C" void kernel_launch(void* const* d_in, const int* in_sizes, int n_in,
                              void* d_out, int out_size, void* d_ws, size_t ws_size,
                              hipStream_t stream)
{
    const float* em     = (const float*)d_in[0];
    const int*   tags   = (const int*)d_in[1];
    const int*   mask   = (const int*)d_in[2];
    const float* startT = (const float*)d_in[3];
    const float* endT   = (const float*)d_in[4];
    const float* trans  = (const float*)d_in[5];
    float*       out    = (float*)d_out;

    (void)d_ws; (void)ws_size;

    hipMemsetAsync(out, 0, sizeof(float) * out_size, stream);
    crf_kernel<<<BATCH, 128, 0, stream>>>(em, tags, mask, startT, endT, trans, out);
}

// Round 5
// 346.693 us; speedup vs baseline: 1.0063x; 1.0063x over previous
//
#include <hip/hip_runtime.h>

#define SEQ 1024
#define BATCH 512
#define NTAGS 64
#define HALF_T 512
#define LOGD 4.158883083f   // log(64): per-step damp folded into exp(em)

typedef _Float16 v2h __attribute__((ext_vector_type(2)));

__device__ __forceinline__ float dot2acc(v2h a, v2h b, float c) {
#if __has_builtin(__builtin_amdgcn_fdot2)
    return __builtin_amdgcn_fdot2(a, b, c, false);
#else
    return fmaf((float)a.x, (float)b.x, fmaf((float)a.y, (float)b.y, c));
#endif
}

__device__ __forceinline__ float rfl(float x) {
    return __uint_as_float(__builtin_amdgcn_readfirstlane(__float_as_uint(x)));
}

template<int CTRL>
__device__ __forceinline__ unsigned dppmov(unsigned v) {
    return (unsigned)__builtin_amdgcn_mov_dpp((int)v, CTRL, 0xf, 0xf, false);
}

// Pair across the 32-lane boundary: after this, {a,b} hold {x_l, x_{l^32}}
// in a lane-dependent order. Order is irrelevant: the weight layout is
// derived by running the IDENTICAL ops on lane indices at init.
// NOTE: builtin returns a NATIVE vector (vector_size(8)) -> index with [0]/[1].
__device__ __forceinline__ void swap32pair(unsigned x, unsigned& a, unsigned& b) {
#if __has_builtin(__builtin_amdgcn_permlane32_swap)
    auto r = __builtin_amdgcn_permlane32_swap(x, x, false, false);
    a = (unsigned)r[0]; b = (unsigned)r[1];
#else
    a = x; b = (unsigned)__shfl_xor((int)x, 32);
#endif
}

__device__ __forceinline__ void swap16pair(unsigned x, unsigned& a, unsigned& b) {
#if __has_builtin(__builtin_amdgcn_permlane16_swap)
    auto r = __builtin_amdgcn_permlane16_swap(x, x, false, false);
    a = (unsigned)r[0]; b = (unsigned)r[1];
#else
    a = x; b = (unsigned)__shfl_xor((int)x, 16);
#endif
}

// Doubling butterfly: 1 packed reg (2 vals) -> 32 regs (all 64 vals).
// Levels: 16-swap, row_mirror (0x140), row_half_mirror (0x141),
// quad_perm xor2 (0x4E), quad_perm xor1 (0xB1). XOR-offset set
// {0,16}x{0,15}x{0,7}x{0,2}x{0,1} covers 0..31 bijectively per 32-half.
// Delivery order is lane-dependent but mirrored exactly by the index
// butterfly at init.
__device__ __forceinline__ void expand64(unsigned p0, unsigned u[32]) {
    swap16pair(p0, u[0], u[1]);
    u[2] = dppmov<0x140>(u[0]);
    u[3] = dppmov<0x140>(u[1]);
#pragma unroll
    for (int k = 0; k < 4; ++k)  u[4 + k]  = dppmov<0x141>(u[k]);
#pragma unroll
    for (int k = 0; k < 8; ++k)  u[8 + k]  = dppmov<0x4E>(u[k]);
#pragma unroll
    for (int k = 0; k < 16; ++k) u[16 + k] = dppmov<0xB1>(u[k]);
}

// Broadcast one fp32 per lane -> 32 fp16-pair regs holding all 64 lanes' values.
__device__ __forceinline__ void bcast64(float x, v2h p[32]) {
    unsigned a, b;
    swap32pair(__float_as_uint(x), a, b);
#if __has_builtin(__builtin_amdgcn_cvt_pkrtz)
    auto pk_ = __builtin_amdgcn_cvt_pkrtz(__uint_as_float(a), __uint_as_float(b));
    unsigned pk = __builtin_bit_cast(unsigned, pk_);
#else
    v2h pkv; pkv.x = (_Float16)__uint_as_float(a); pkv.y = (_Float16)__uint_as_float(b);
    unsigned pk = __builtin_bit_cast(unsigned, pkv);
#endif
    unsigned u[32];
    expand64(pk, u);
#pragma unroll
    for (int s = 0; s < 32; ++s) p[s] = __builtin_bit_cast(v2h, u[s]);
}

// Fused CRF kernel: block b runs BOTH chains of batch b.
//   wave0 (fwd): t = 1..min(L-1,511);  wave1 (bwd): t = L-1..512 descending.
// The per-step 64-wide broadcast is a pure-VALU butterfly (permlane+DPP),
// no LDS on the critical path. Weight layout matches the butterfly's
// delivery order by running the same butterfly on lane indices at init.
//
// __launch_bounds__(128, 1): min 1 wave/EU -> full VGPR budget. The live
// set is ~100 VGPRs (w[32] + butterfly + em pipeline); without this hint
// the compiler allocated 60 and shuffled the rest through AGPRs/scratch
// on the serial critical path (R4: 930 cyc/step vs ~200 theoretical).
__global__ __launch_bounds__(128, 1)
void crf_kernel(const float* __restrict__ em,
                const int* __restrict__ tags,
                const int* __restrict__ mask,
                const float* __restrict__ startT,
                const float* __restrict__ endT,
                const float* __restrict__ trans,
                float* __restrict__ out)
{
    const int  b   = blockIdx.x;
    const int  wid = threadIdx.x >> 6;
    const int  j   = threadIdx.x & 63;
    const bool fwd = (wid == 0);

    __shared__ float gsh[NTAGS];   // gamma from bwd wave
    __shared__ float mb_np[2];     // [0]=Mb, [1]=np partial (bwd)

    // chain length = sum of this batch's mask column
    int lsum = 0;
#pragma unroll
    for (int k = 0; k < SEQ / 64; ++k)
        lsum += mask[(k * 64 + j) * BATCH + b];
#pragma unroll
    for (int off = 32; off > 0; off >>= 1)
        lsum += __shfl_xor(lsum, off);
    const int L = lsum;

    // Index butterfly: find which beta-index lands in each slot/component.
    unsigned I[32];
    {
        unsigned ia, ib;
        swap32pair((unsigned)j, ia, ib);
        unsigned i0 = (ia & 0xffffu) | (ib << 16);
        expand64(i0, I);
    }

    // fp16 expT fragment matched to the butterfly delivery order:
    // fwd lane j needs column j (T[i][j]); bwd lane j needs row j (T[j][i]).
    v2h w[32];
#pragma unroll
    for (int s = 0; s < 32; ++s) {
        unsigned i0 = I[s] & 0xffffu;
        unsigned i1 = I[s] >> 16;
        float a0 = fwd ? trans[i0 * NTAGS + j] : trans[j * NTAGS + i0];
        float a1 = fwd ? trans[i1 * NTAGS + j] : trans[j * NTAGS + i1];
        v2h t; t.x = (_Float16)__expf(a0); t.y = (_Float16)__expf(a1);
        w[s] = t;
    }

#define DOT(WRVAL, SOUT)                                                   \
    {                                                                      \
        v2h p_[32];                                                        \
        bcast64((WRVAL), p_);                                              \
        float s0 = 0.f, s1 = 0.f, s2 = 0.f, s3 = 0.f;                      \
        float s4 = 0.f, s5 = 0.f, s6 = 0.f, s7 = 0.f;                      \
        _Pragma("unroll")                                                  \
        for (int q = 0; q < 4; ++q) {                                      \
            s0 = dot2acc(p_[8 * q + 0], w[8 * q + 0], s0);                 \
            s1 = dot2acc(p_[8 * q + 1], w[8 * q + 1], s1);                 \
            s2 = dot2acc(p_[8 * q + 2], w[8 * q + 2], s2);                 \
            s3 = dot2acc(p_[8 * q + 3], w[8 * q + 3], s3);                 \
            s4 = dot2acc(p_[8 * q + 4], w[8 * q + 4], s4);                 \
            s5 = dot2acc(p_[8 * q + 5], w[8 * q + 5], s5);                 \
            s6 = dot2acc(p_[8 * q + 6], w[8 * q + 6], s6);                 \
            s7 = dot2acc(p_[8 * q + 7], w[8 * q + 7], s7);                 \
        }                                                                  \
        SOUT = ((s0 + s1) + (s2 + s3)) + ((s4 + s5) + (s6 + s7));          \
    }

    float beta, M;
    int nsteps = 0;

    if (fwd) {
        float em0 = em[(size_t)b * NTAGS + j];
        float a0  = startT[j] + em0;
        M    = __shfl(a0, 0);
        beta = __expf(a0 - M);

        const int Lf = min(L - 1, HALF_T - 1);   // active steps t=1..Lf
        int t = 1;
        float cur[4], nxt[4];
#pragma unroll
        for (int u = 0; u < 4; ++u) {
            cur[u] = em[((size_t)min(t + u,     SEQ - 1) * BATCH + b) * NTAGS + j];
            nxt[u] = em[((size_t)min(t + 4 + u, SEQ - 1) * BATCH + b) * NTAGS + j];
        }
        while (t + 3 <= Lf) {
            float pre[4];
#pragma unroll
            for (int u = 0; u < 4; ++u)
                pre[u] = em[((size_t)min(t + 8 + u, SEQ - 1) * BATCH + b) * NTAGS + j];
            float eem[4];
#pragma unroll
            for (int u = 0; u < 4; ++u) eem[u] = __expf(cur[u] - LOGD);

            float s;
            DOT(beta, s); beta = s * eem[0];
            DOT(beta, s);
            float r = rfl(s);                 // uniform-ish positive renorm scale
            beta = s * eem[1];
            DOT(beta, s); beta = s * eem[2];
            float rinv = 1.0f / r;            // off-path
            float lr   = __logf(r);           // off-path
            DOT(beta, s); beta = s * (eem[3] * rinv);
            M += lr;
            nsteps += 4;
#pragma unroll
            for (int u = 0; u < 4; ++u) { cur[u] = nxt[u]; nxt[u] = pre[u]; }
            t += 4;
        }
        for (; t <= Lf; ++t) {
            float emt = em[((size_t)t * BATCH + b) * NTAGS + j];
            float s; DOT(beta, s);
            beta = s * __expf(emt - LOGD);
            ++nsteps;
        }
    } else {
        beta = __expf(endT[j]);               // B_j init (frozen for t >= L)
        M = 0.0f;
        if (L - 1 >= HALF_T) {
            int tt = L - 1;                   // steps tt = L-1 .. 512 descending
            float cur[4], nxt[4];
#pragma unroll
            for (int u = 0; u < 4; ++u) {
                cur[u] = em[((size_t)max(tt - u,     0) * BATCH + b) * NTAGS + j];
                nxt[u] = em[((size_t)max(tt - 4 - u, 0) * BATCH + b) * NTAGS + j];
            }
            while (tt - 3 >= HALF_T) {
                float pre[4];
#pragma unroll
                for (int u = 0; u < 4; ++u)
                    pre[u] = em[((size_t)max(tt - 8 - u, 0) * BATCH + b) * NTAGS + j];
                float eem[4];
#pragma unroll
                for (int u = 0; u < 4; ++u) eem[u] = __expf(cur[u] - LOGD);

                float s;
                DOT(beta * eem[0], s); beta = s;
                DOT(beta * eem[1], s);
                float r = rfl(s);
                beta = s;
                DOT(beta * eem[2], s); beta = s;
                float rinv = 1.0f / r;
                float lr   = __logf(r);
                DOT(beta * (eem[3] * rinv), s); beta = s;
                M += lr;
                nsteps += 4;
#pragma unroll
                for (int u = 0; u < 4; ++u) { cur[u] = nxt[u]; nxt[u] = pre[u]; }
                tt -= 4;
            }
            for (; tt >= HALF_T; --tt) {
                float emt = em[((size_t)tt * BATCH + b) * NTAGS + j];
                float s; DOT(beta * __expf(emt - LOGD), s);
                beta = s;
                ++nsteps;
            }
        }
    }
#undef DOT

    const float Mfb = fmaf((float)nsteps, LOGD, M);  // per-wave log-scale

    if (!fwd) {
        gsh[j] = beta;                      // gamma vector
        if (j == 0) mb_np[0] = Mfb;         // Mb
    }

    // numerator partial: thread tid handles t = k*128 + tid
    float np = 0.0f;
#pragma unroll
    for (int k = 0; k < SEQ / 128; ++k) {
        int t = k * 128 + wid * 64 + j;
        if (t >= 1 && t < L) {
            int ct = tags[t * BATCH + b];
            int pt = tags[(t - 1) * BATCH + b];
            np += trans[pt * NTAGS + ct] + em[((size_t)t * BATCH + b) * NTAGS + ct];
        }
    }
    if (threadIdx.x == 0) {
        int t0 = tags[b];
        np += startT[t0] + em[(size_t)b * NTAGS + t0]
            + endT[tags[(size_t)(L - 1) * BATCH + b]];
    }
#pragma unroll
    for (int off = 32; off > 0; off >>= 1)
        np += __shfl_xor(np, off);
    if (!fwd && j == 0) mb_np[1] = np;

    __syncthreads();

    if (fwd) {
        float p = beta * gsh[j];            // midpoint dot: beta_f . gamma
#pragma unroll
        for (int off = 32; off > 0; off >>= 1)
            p += __shfl_xor(p, off);
        if (j == 0) {
            float denom = __logf(p) + Mfb + mb_np[0];
            atomicAdd(out, (np + mb_np[1]) - denom);
        }
    }
}

extern "C" void kernel_launch(void* const* d_in, const int* in_sizes, int n_in,
                              void* d_out, int out_size, void* d_ws, size_t ws_size,
                              hipStream_t stream)
{
    const float* em     = (const float*)d_in[0];
    const int*   tags   = (const int*)d_in[1];
    const int*   mask   = (const int*)d_in[2];
    const float* startT = (const float*)d_in[3];
    const float* endT   = (const float*)d_in[4];
    const float* trans  = (const float*)d_in[5];
    float*       out    = (float*)d_out;

    (void)d_ws; (void)ws_size;

    hipMemsetAsync(out, 0, sizeof(float) * out_size, stream);
    crf_kernel<<<BATCH, 128, 0, stream>>>(em, tags, mask, startT, endT, trans, out);
}